// Round 1
// baseline (553.307 us; speedup 1.0000x reference)
//
#include <hip/hip_runtime.h>

// ---------------------------------------------------------------------------
// GCN: h1 = relu(Agg(x@W1)+b1); h2 = relu(Agg(h1@W2)+b2); out = h2@Wfc+bfc
// Agg(h)[i] = sum_{e: dst[e]==i} dinv[src]*w*dinv[i] * h[src] + dinv[i]^2*h[i]
// deg[i] = 1 + sum_{e: dst[e]==i} w[e]   (self-loop weight 1)
// Strategy: build CSR-by-dst each launch (histogram+scan+scatter), then
// gather-based aggregation (no feature atomics). GEMMs are fp32 vector-ALU
// with W + X-tile in LDS (no fp32 MFMA on CDNA4).
// ---------------------------------------------------------------------------

__global__ __launch_bounds__(256) void k_init_nodes(float* deg, int* counts, int n) {
    int i = blockIdx.x * 256 + threadIdx.x;
    if (i < n) { deg[i] = 1.0f; counts[i] = 0; }
}

__global__ __launch_bounds__(256) void k_edge_deg(const int* __restrict__ dst,
                                                  const float* __restrict__ w,
                                                  float* deg, int* counts, int E) {
    int e = blockIdx.x * 256 + threadIdx.x;
    if (e < E) {
        int d = dst[e];
        atomicAdd(&deg[d], w[e]);
        atomicAdd(&counts[d], 1);
    }
}

__global__ __launch_bounds__(256) void k_dinv(const float* __restrict__ deg,
                                              float* dinv, int n) {
    int i = blockIdx.x * 256 + threadIdx.x;
    if (i < n) dinv[i] = rsqrtf(deg[i]);  // deg >= 1 always (self-loop)
}

// Single-block exclusive scan of counts -> rowptr (and cursor copy).
__global__ __launch_bounds__(1024) void k_scan(const int* __restrict__ counts,
                                               int* rowptr, int* cursor, int n) {
    __shared__ int sums[1024];
    int t = threadIdx.x;
    int chunk = (n + 1023) >> 10;          // 49 for n=50000
    int start = t * chunk;
    int end = min(start + chunk, n);
    int s = 0;
    for (int i = start; i < end; i++) s += counts[i];
    sums[t] = s;
    __syncthreads();
    for (int off = 1; off < 1024; off <<= 1) {
        int v = (t >= off) ? sums[t - off] : 0;
        __syncthreads();
        sums[t] += v;
        __syncthreads();
    }
    int excl = (t == 0) ? 0 : sums[t - 1];
    for (int i = start; i < end; i++) {
        rowptr[i] = excl;
        cursor[i] = excl;
        excl += counts[i];
    }
    if (t == 1023) rowptr[n] = sums[1023];
}

__global__ __launch_bounds__(256) void k_scatter(const int* __restrict__ src,
                                                 const int* __restrict__ dst,
                                                 const float* __restrict__ w,
                                                 const float* __restrict__ dinv,
                                                 int* cursor, int* col, float* val, int E) {
    int e = blockIdx.x * 256 + threadIdx.x;
    if (e < E) {
        int s = src[e], d = dst[e];
        int p = atomicAdd(&cursor[d], 1);
        col[p] = s;
        val[p] = dinv[s] * w[e] * dinv[d];
    }
}

// Y[r,:] = X[r,:] @ W (+bias). W is 128x128. 32 rows per block.
// LDS: W 64KB + X-tile 16KB = 80KB -> 2 blocks/CU. Safe to run in-place
// (X==Y): each block stages its own rows into LDS before any store.
__global__ __launch_bounds__(256) void k_gemm128(const float* __restrict__ X,
                                                 const float* __restrict__ W,
                                                 const float* __restrict__ bias,
                                                 float* __restrict__ Y,
                                                 int n, int add_bias) {
    __shared__ __align__(16) float Ws[128 * 128];
    __shared__ __align__(16) float Xs[32 * 128];
    int t = threadIdx.x;
    {   // stage W (row-major [k][c]) : 4096 float4
        const float4* W4 = (const float4*)W;
        float4* Ws4 = (float4*)Ws;
#pragma unroll
        for (int i = 0; i < 16; i++) Ws4[t + i * 256] = W4[t + i * 256];
    }
    int row0 = blockIdx.x * 32;
    {   // stage X tile: 32 rows x 128 (zeros past n)
        float4* Xs4 = (float4*)Xs;
        for (int i = t; i < 32 * 32; i += 256) {
            int r = i >> 5, c = i & 31;
            int gr = row0 + r;
            float4 v = make_float4(0.f, 0.f, 0.f, 0.f);
            if (gr < n) v = ((const float4*)(X + (size_t)gr * 128))[c];
            Xs4[i] = v;
        }
    }
    __syncthreads();

    int tx = t & 31;   // col group: cols tx*4 .. tx*4+3
    int ty = t >> 5;   // row group: rows ty*4 .. ty*4+3
    float acc[4][4];
#pragma unroll
    for (int r = 0; r < 4; r++)
#pragma unroll
        for (int c = 0; c < 4; c++) acc[r][c] = 0.f;

    const float4* Ws4 = (const float4*)Ws;
    const float4* Xs4 = (const float4*)Xs;
#pragma unroll 4
    for (int k = 0; k < 128; k += 4) {
        float4 w0 = Ws4[(k + 0) * 32 + tx];
        float4 w1 = Ws4[(k + 1) * 32 + tx];
        float4 w2 = Ws4[(k + 2) * 32 + tx];
        float4 w3 = Ws4[(k + 3) * 32 + tx];
#pragma unroll
        for (int r = 0; r < 4; r++) {
            float4 xv = Xs4[(ty * 4 + r) * 32 + (k >> 2)];
            acc[r][0] = fmaf(xv.x, w0.x, acc[r][0]);
            acc[r][0] = fmaf(xv.y, w1.x, acc[r][0]);
            acc[r][0] = fmaf(xv.z, w2.x, acc[r][0]);
            acc[r][0] = fmaf(xv.w, w3.x, acc[r][0]);
            acc[r][1] = fmaf(xv.x, w0.y, acc[r][1]);
            acc[r][1] = fmaf(xv.y, w1.y, acc[r][1]);
            acc[r][1] = fmaf(xv.z, w2.y, acc[r][1]);
            acc[r][1] = fmaf(xv.w, w3.y, acc[r][1]);
            acc[r][2] = fmaf(xv.x, w0.z, acc[r][2]);
            acc[r][2] = fmaf(xv.y, w1.z, acc[r][2]);
            acc[r][2] = fmaf(xv.z, w2.z, acc[r][2]);
            acc[r][2] = fmaf(xv.w, w3.z, acc[r][2]);
            acc[r][3] = fmaf(xv.x, w0.w, acc[r][3]);
            acc[r][3] = fmaf(xv.y, w1.w, acc[r][3]);
            acc[r][3] = fmaf(xv.z, w2.w, acc[r][3]);
            acc[r][3] = fmaf(xv.w, w3.w, acc[r][3]);
        }
    }

    float4 bv = make_float4(0.f, 0.f, 0.f, 0.f);
    if (add_bias) bv = ((const float4*)bias)[tx];
#pragma unroll
    for (int r = 0; r < 4; r++) {
        int gr = row0 + ty * 4 + r;
        if (gr < n) {
            float4 o = make_float4(acc[r][0] + bv.x, acc[r][1] + bv.y,
                                   acc[r][2] + bv.z, acc[r][3] + bv.w);
            ((float4*)(Y + (size_t)gr * 128))[tx] = o;
        }
    }
}

// One wave per node; lane holds 2 features (float2 -> 512B coalesced rows).
// out[i] = maybe_relu( sum_e val[e]*H[col[e]] + dinv[i]^2*H[i] + bias )
__global__ __launch_bounds__(256) void k_agg(const float* __restrict__ H,
                                             const int* __restrict__ rowptr,
                                             const int* __restrict__ col,
                                             const float* __restrict__ val,
                                             const float* __restrict__ dinv,
                                             const float* __restrict__ bias,
                                             float* __restrict__ out,
                                             int n, int do_relu) {
    int wid = (blockIdx.x * 256 + threadIdx.x) >> 6;
    int lane = threadIdx.x & 63;
    if (wid >= n) return;
    int i = __builtin_amdgcn_readfirstlane(wid);  // wave-uniform -> scalar loads
    float di = dinv[i];
    float2 h0 = ((const float2*)(H + (size_t)i * 128))[lane];
    float w0 = di * di;
    float ax = w0 * h0.x, ay = w0 * h0.y;
    int e0 = rowptr[i], e1 = rowptr[i + 1];
    for (int e = e0; e < e1; e++) {
        int s = col[e];
        float v = val[e];
        float2 h = ((const float2*)(H + (size_t)s * 128))[lane];
        ax = fmaf(v, h.x, ax);
        ay = fmaf(v, h.y, ay);
    }
    float2 b = ((const float2*)bias)[lane];
    ax += b.x; ay += b.y;
    if (do_relu) { ax = fmaxf(ax, 0.f); ay = fmaxf(ay, 0.f); }
    ((float2*)(out + (size_t)i * 128))[lane] = make_float2(ax, ay);
}

extern "C" void kernel_launch(void* const* d_in, const int* in_sizes, int n_in,
                              void* d_out, int out_size, void* d_ws, size_t ws_size,
                              hipStream_t stream) {
    const float* x   = (const float*)d_in[0];
    const float* ew  = (const float*)d_in[1];
    const float* W1  = (const float*)d_in[2];
    const float* b1  = (const float*)d_in[3];
    const float* W2  = (const float*)d_in[4];
    const float* b2  = (const float*)d_in[5];
    const float* Wfc = (const float*)d_in[6];
    const float* bfc = (const float*)d_in[7];
    const int* eidx  = (const int*)d_in[8];

    const int E = in_sizes[1];
    const int N = in_sizes[0] / 128;
    const int* src = eidx;       // edge_index row 0
    const int* dst = eidx + E;   // edge_index row 1

    char* ws = (char*)d_ws;
    size_t off = 0;
    auto alloc = [&](size_t bytes) -> void* {
        void* p = ws + off;
        off = (off + bytes + 255) & ~(size_t)255;
        return p;
    };
    float* deg    = (float*)alloc((size_t)N * 4);
    float* dinv   = (float*)alloc((size_t)N * 4);
    int*   counts = (int*)alloc((size_t)N * 4);
    int*   cursor = (int*)alloc((size_t)N * 4);
    int*   rowptr = (int*)alloc((size_t)(N + 1) * 4);
    int*   col    = (int*)alloc((size_t)E * 4);
    float* val    = (float*)alloc((size_t)E * 4);
    float* buf0   = (float*)alloc((size_t)N * 128 * 4);
    float* out    = (float*)d_out;

    int nb = (N + 255) / 256;
    int eb = (E + 255) / 256;
    int gb = (N + 31) / 32;
    int ab = (N * 64 + 255) / 256;

    // Graph prep (re-done every launch; no state caching)
    k_init_nodes<<<nb, 256, 0, stream>>>(deg, counts, N);
    k_edge_deg<<<eb, 256, 0, stream>>>(dst, ew, deg, counts, E);
    k_dinv<<<nb, 256, 0, stream>>>(deg, dinv, N);
    k_scan<<<1, 1024, 0, stream>>>(counts, rowptr, cursor, N);
    k_scatter<<<eb, 256, 0, stream>>>(src, dst, ew, dinv, cursor, col, val, E);

    // Layer 1
    k_gemm128<<<gb, 256, 0, stream>>>(x, W1, nullptr, buf0, N, 0);
    k_agg<<<ab, 256, 0, stream>>>(buf0, rowptr, col, val, dinv, b1, out, N, 1);
    // Layer 2
    k_gemm128<<<gb, 256, 0, stream>>>(out, W2, nullptr, buf0, N, 0);
    k_agg<<<ab, 256, 0, stream>>>(buf0, rowptr, col, val, dinv, b2, out, N, 1);
    // FC (in-place on d_out: block stages its rows to LDS before storing)
    k_gemm128<<<gb, 256, 0, stream>>>(out, Wfc, bfc, out, N, 1);
}

// Round 2
// 452.175 us; speedup vs baseline: 1.2237x; 1.2237x over previous
//
#include <hip/hip_runtime.h>

// ---------------------------------------------------------------------------
// GCN: h1 = relu(Agg(x@W1)+b1); h2 = relu(Agg(h1@W2)+b2); out = h2@Wfc+bfc
// Agg(h)[i] = sum_{e: dst[e]==i} dinv[src]*w*dinv[i] * h[src] + dinv[i]^2*h[i]
// CSR-by-dst built per launch. R1: replaced 111us single-block scan with
// 3-phase multi-block scan (all CUs); fused dinv into phase 1.
// ---------------------------------------------------------------------------

__global__ __launch_bounds__(256) void k_init_nodes(float* deg, int* counts, int n) {
    int i = blockIdx.x * 256 + threadIdx.x;
    if (i < n) { deg[i] = 1.0f; counts[i] = 0; }
}

__global__ __launch_bounds__(256) void k_edge_deg(const int* __restrict__ dst,
                                                  const float* __restrict__ w,
                                                  float* deg, int* counts, int E) {
    int e = blockIdx.x * 256 + threadIdx.x;
    if (e < E) {
        int d = dst[e];
        atomicAdd(&deg[d], w[e]);
        atomicAdd(&counts[d], 1);
    }
}

// Phase 1: per-block sum of counts -> bsum[block]; fused dinv = rsqrt(deg).
__global__ __launch_bounds__(256) void k_part(const float* __restrict__ deg,
                                              float* __restrict__ dinv,
                                              const int* __restrict__ counts,
                                              int* __restrict__ bsum, int n) {
    __shared__ int red[256];
    int t = threadIdx.x;
    int i = blockIdx.x * 256 + t;
    int c = (i < n) ? counts[i] : 0;
    if (i < n) dinv[i] = rsqrtf(deg[i]);   // deg >= 1 (self-loop)
    red[t] = c;
    __syncthreads();
#pragma unroll
    for (int off = 128; off > 0; off >>= 1) {
        if (t < off) red[t] += red[t + off];
        __syncthreads();
    }
    if (t == 0) bsum[blockIdx.x] = red[0];
}

// Phase 2: single block exclusive-scans bsum (nb <= 256 for N=50000).
__global__ __launch_bounds__(256) void k_scan_bsums(int* bsum, int nb) {
    __shared__ int s[256];
    int t = threadIdx.x;
    s[t] = (t < nb) ? bsum[t] : 0;
    __syncthreads();
#pragma unroll
    for (int off = 1; off < 256; off <<= 1) {
        int u = (t >= off) ? s[t - off] : 0;
        __syncthreads();
        s[t] += u;
        __syncthreads();
    }
    if (t < nb) bsum[t] = (t == 0) ? 0 : s[t - 1];
}

// Phase 3: block-local inclusive scan + bsum offset -> rowptr/cursor.
__global__ __launch_bounds__(256) void k_rowptr(const int* __restrict__ counts,
                                                const int* __restrict__ bsum,
                                                int* __restrict__ rowptr,
                                                int* __restrict__ cursor, int n) {
    __shared__ int s[256];
    int t = threadIdx.x;
    int i = blockIdx.x * 256 + t;
    int c = (i < n) ? counts[i] : 0;
    s[t] = c;
    __syncthreads();
#pragma unroll
    for (int off = 1; off < 256; off <<= 1) {
        int u = (t >= off) ? s[t - off] : 0;
        __syncthreads();
        s[t] += u;
        __syncthreads();
    }
    int excl = bsum[blockIdx.x] + s[t] - c;
    if (i < n) { rowptr[i] = excl; cursor[i] = excl; }
    if (i == n - 1) rowptr[n] = excl + c;
}

__global__ __launch_bounds__(256) void k_scatter(const int* __restrict__ src,
                                                 const int* __restrict__ dst,
                                                 const float* __restrict__ w,
                                                 const float* __restrict__ dinv,
                                                 int* cursor, int* col, float* val, int E) {
    int e = blockIdx.x * 256 + threadIdx.x;
    if (e < E) {
        int s = src[e], d = dst[e];
        int p = atomicAdd(&cursor[d], 1);
        col[p] = s;
        val[p] = dinv[s] * w[e] * dinv[d];
    }
}

// Y[r,:] = X[r,:] @ W (+bias). W is 128x128. 32 rows per block.
// LDS: W 64KB + X-tile 16KB = 80KB -> 2 blocks/CU. Safe in-place (X==Y):
// block stages its rows into LDS before any store.
__global__ __launch_bounds__(256) void k_gemm128(const float* __restrict__ X,
                                                 const float* __restrict__ W,
                                                 const float* __restrict__ bias,
                                                 float* __restrict__ Y,
                                                 int n, int add_bias) {
    __shared__ __align__(16) float Ws[128 * 128];
    __shared__ __align__(16) float Xs[32 * 128];
    int t = threadIdx.x;
    {   // stage W (row-major [k][c]) : 4096 float4
        const float4* W4 = (const float4*)W;
        float4* Ws4 = (float4*)Ws;
#pragma unroll
        for (int i = 0; i < 16; i++) Ws4[t + i * 256] = W4[t + i * 256];
    }
    int row0 = blockIdx.x * 32;
    {   // stage X tile: 32 rows x 128 (zeros past n)
        float4* Xs4 = (float4*)Xs;
        for (int i = t; i < 32 * 32; i += 256) {
            int r = i >> 5, c = i & 31;
            int gr = row0 + r;
            float4 v = make_float4(0.f, 0.f, 0.f, 0.f);
            if (gr < n) v = ((const float4*)(X + (size_t)gr * 128))[c];
            Xs4[i] = v;
        }
    }
    __syncthreads();

    int tx = t & 31;   // cols tx*4 .. tx*4+3
    int ty = t >> 5;   // rows ty*4 .. ty*4+3
    float acc[4][4];
#pragma unroll
    for (int r = 0; r < 4; r++)
#pragma unroll
        for (int c = 0; c < 4; c++) acc[r][c] = 0.f;

    const float4* Ws4 = (const float4*)Ws;
    const float4* Xs4 = (const float4*)Xs;
#pragma unroll 4
    for (int k = 0; k < 128; k += 4) {
        float4 w0 = Ws4[(k + 0) * 32 + tx];
        float4 w1 = Ws4[(k + 1) * 32 + tx];
        float4 w2 = Ws4[(k + 2) * 32 + tx];
        float4 w3 = Ws4[(k + 3) * 32 + tx];
#pragma unroll
        for (int r = 0; r < 4; r++) {
            float4 xv = Xs4[(ty * 4 + r) * 32 + (k >> 2)];
            acc[r][0] = fmaf(xv.x, w0.x, acc[r][0]);
            acc[r][0] = fmaf(xv.y, w1.x, acc[r][0]);
            acc[r][0] = fmaf(xv.z, w2.x, acc[r][0]);
            acc[r][0] = fmaf(xv.w, w3.x, acc[r][0]);
            acc[r][1] = fmaf(xv.x, w0.y, acc[r][1]);
            acc[r][1] = fmaf(xv.y, w1.y, acc[r][1]);
            acc[r][1] = fmaf(xv.z, w2.y, acc[r][1]);
            acc[r][1] = fmaf(xv.w, w3.y, acc[r][1]);
            acc[r][2] = fmaf(xv.x, w0.z, acc[r][2]);
            acc[r][2] = fmaf(xv.y, w1.z, acc[r][2]);
            acc[r][2] = fmaf(xv.z, w2.z, acc[r][2]);
            acc[r][2] = fmaf(xv.w, w3.z, acc[r][2]);
            acc[r][3] = fmaf(xv.x, w0.w, acc[r][3]);
            acc[r][3] = fmaf(xv.y, w1.w, acc[r][3]);
            acc[r][3] = fmaf(xv.z, w2.w, acc[r][3]);
            acc[r][3] = fmaf(xv.w, w3.w, acc[r][3]);
        }
    }

    float4 bv = make_float4(0.f, 0.f, 0.f, 0.f);
    if (add_bias) bv = ((const float4*)bias)[tx];
#pragma unroll
    for (int r = 0; r < 4; r++) {
        int gr = row0 + ty * 4 + r;
        if (gr < n) {
            float4 o = make_float4(acc[r][0] + bv.x, acc[r][1] + bv.y,
                                   acc[r][2] + bv.z, acc[r][3] + bv.w);
            ((float4*)(Y + (size_t)gr * 128))[tx] = o;
        }
    }
}

// One wave per node; lane holds 2 features (float2 -> 512B coalesced rows).
__global__ __launch_bounds__(256) void k_agg(const float* __restrict__ H,
                                             const int* __restrict__ rowptr,
                                             const int* __restrict__ col,
                                             const float* __restrict__ val,
                                             const float* __restrict__ dinv,
                                             const float* __restrict__ bias,
                                             float* __restrict__ out,
                                             int n, int do_relu) {
    int wid = (blockIdx.x * 256 + threadIdx.x) >> 6;
    int lane = threadIdx.x & 63;
    if (wid >= n) return;
    int i = __builtin_amdgcn_readfirstlane(wid);  // wave-uniform -> scalar loads
    float di = dinv[i];
    float2 h0 = ((const float2*)(H + (size_t)i * 128))[lane];
    float w0 = di * di;
    float ax = w0 * h0.x, ay = w0 * h0.y;
    int e0 = rowptr[i], e1 = rowptr[i + 1];
    for (int e = e0; e < e1; e++) {
        int s = col[e];
        float v = val[e];
        float2 h = ((const float2*)(H + (size_t)s * 128))[lane];
        ax = fmaf(v, h.x, ax);
        ay = fmaf(v, h.y, ay);
    }
    float2 b = ((const float2*)bias)[lane];
    ax += b.x; ay += b.y;
    if (do_relu) { ax = fmaxf(ax, 0.f); ay = fmaxf(ay, 0.f); }
    ((float2*)(out + (size_t)i * 128))[lane] = make_float2(ax, ay);
}

extern "C" void kernel_launch(void* const* d_in, const int* in_sizes, int n_in,
                              void* d_out, int out_size, void* d_ws, size_t ws_size,
                              hipStream_t stream) {
    const float* x   = (const float*)d_in[0];
    const float* ew  = (const float*)d_in[1];
    const float* W1  = (const float*)d_in[2];
    const float* b1  = (const float*)d_in[3];
    const float* W2  = (const float*)d_in[4];
    const float* b2  = (const float*)d_in[5];
    const float* Wfc = (const float*)d_in[6];
    const float* bfc = (const float*)d_in[7];
    const int* eidx  = (const int*)d_in[8];

    const int E = in_sizes[1];
    const int N = in_sizes[0] / 128;
    const int* src = eidx;       // edge_index row 0
    const int* dst = eidx + E;   // edge_index row 1

    char* ws = (char*)d_ws;
    size_t off = 0;
    auto alloc = [&](size_t bytes) -> void* {
        void* p = ws + off;
        off = (off + bytes + 255) & ~(size_t)255;
        return p;
    };
    int nb = (N + 255) / 256;    // 196 for N=50000 (must be <= 256)
    int eb = (E + 255) / 256;
    int gb = (N + 31) / 32;
    int ab = (N * 64 + 255) / 256;

    float* deg    = (float*)alloc((size_t)N * 4);
    float* dinv   = (float*)alloc((size_t)N * 4);
    int*   counts = (int*)alloc((size_t)N * 4);
    int*   cursor = (int*)alloc((size_t)N * 4);
    int*   rowptr = (int*)alloc((size_t)(N + 1) * 4);
    int*   bsum   = (int*)alloc((size_t)nb * 4);
    int*   col    = (int*)alloc((size_t)E * 4);
    float* val    = (float*)alloc((size_t)E * 4);
    float* buf0   = (float*)alloc((size_t)N * 128 * 4);
    float* out    = (float*)d_out;

    // Graph prep (re-done every launch; no state caching)
    k_init_nodes<<<nb, 256, 0, stream>>>(deg, counts, N);
    k_edge_deg<<<eb, 256, 0, stream>>>(dst, ew, deg, counts, E);
    k_part<<<nb, 256, 0, stream>>>(deg, dinv, counts, bsum, N);
    k_scan_bsums<<<1, 256, 0, stream>>>(bsum, nb);
    k_rowptr<<<nb, 256, 0, stream>>>(counts, bsum, rowptr, cursor, N);
    k_scatter<<<eb, 256, 0, stream>>>(src, dst, ew, dinv, cursor, col, val, E);

    // Layer 1
    k_gemm128<<<gb, 256, 0, stream>>>(x, W1, nullptr, buf0, N, 0);
    k_agg<<<ab, 256, 0, stream>>>(buf0, rowptr, col, val, dinv, b1, out, N, 1);
    // Layer 2
    k_gemm128<<<gb, 256, 0, stream>>>(out, W2, nullptr, buf0, N, 0);
    k_agg<<<ab, 256, 0, stream>>>(buf0, rowptr, col, val, dinv, b2, out, N, 1);
    // FC (in-place on d_out: block stages its rows to LDS before storing)
    k_gemm128<<<gb, 256, 0, stream>>>(out, Wfc, bfc, out, N, 1);
}

// Round 3
// 388.383 us; speedup vs baseline: 1.4246x; 1.1642x over previous
//
#include <hip/hip_runtime.h>

// ---------------------------------------------------------------------------
// GCN: h1 = relu(Agg(x@W1)+b1); h2 = relu(Agg(h1@W2)+b2); out = h2@Wfc+bfc
// Agg(h)[i] = sum_{e: dst[e]==i} dinv[src]*w*dinv[i] * h[src] + dinv[i]^2*h[i]
// CSR-by-dst built per launch.
// R1: multi-block scan (553->452us).
// R2: 3 atomics/edge -> 1 packed u64 atomic/edge. Device-scope atomics
// bypass the non-coherent per-XCD L2s (49.8MB HBM WRITE for 400KB of
// histogram state), so atomic count is the cost driver. The u64 atomic
// packs {count:24 | weight-sum fixed-point 16.24:40} and its return value
// doubles as the edge's within-row rank, making the scatter atomic-free.
// ---------------------------------------------------------------------------

typedef unsigned long long u64;

__global__ __launch_bounds__(256) void k_init(u64* packed, int n) {
    int i = blockIdx.x * 256 + threadIdx.x;
    if (i < n) packed[i] = 0ULL;
}

// One u64 atomic per edge: count in bits [40,64), fixed-point weight sum
// (2^24 scale) in bits [0,40). Old value >> 40 = this edge's rank in row.
__global__ __launch_bounds__(256) void k_edge_deg(const int* __restrict__ dst,
                                                  const float* __restrict__ w,
                                                  u64* __restrict__ packed,
                                                  unsigned int* __restrict__ rank, int E) {
    int e = blockIdx.x * 256 + threadIdx.x;
    if (e < E) {
        int d = dst[e];
        u64 add = (1ULL << 40) | (u64)(w[e] * 16777216.0f);
        u64 old = atomicAdd(&packed[d], add);
        rank[e] = (unsigned int)(old >> 40);
    }
}

// Phase 1: per-block sum of counts -> bsum[block]; fused dinv = rsqrt(deg).
__global__ __launch_bounds__(256) void k_part(const u64* __restrict__ packed,
                                              float* __restrict__ dinv,
                                              int* __restrict__ bsum, int n) {
    __shared__ int red[256];
    int t = threadIdx.x;
    int i = blockIdx.x * 256 + t;
    int c = 0;
    if (i < n) {
        u64 p = packed[i];
        c = (int)(p >> 40);
        float degsum = (float)(p & ((1ULL << 40) - 1)) * (1.0f / 16777216.0f);
        dinv[i] = rsqrtf(1.0f + degsum);   // self-loop weight 1
    }
    red[t] = c;
    __syncthreads();
#pragma unroll
    for (int off = 128; off > 0; off >>= 1) {
        if (t < off) red[t] += red[t + off];
        __syncthreads();
    }
    if (t == 0) bsum[blockIdx.x] = red[0];
}

// Phase 2: single block exclusive-scans bsum (nb <= 256 for N=50000).
__global__ __launch_bounds__(256) void k_scan_bsums(int* bsum, int nb) {
    __shared__ int s[256];
    int t = threadIdx.x;
    s[t] = (t < nb) ? bsum[t] : 0;
    __syncthreads();
#pragma unroll
    for (int off = 1; off < 256; off <<= 1) {
        int u = (t >= off) ? s[t - off] : 0;
        __syncthreads();
        s[t] += u;
        __syncthreads();
    }
    if (t < nb) bsum[t] = (t == 0) ? 0 : s[t - 1];
}

// Phase 3: block-local inclusive scan + bsum offset -> rowptr.
__global__ __launch_bounds__(256) void k_rowptr(const u64* __restrict__ packed,
                                                const int* __restrict__ bsum,
                                                int* __restrict__ rowptr, int n) {
    __shared__ int s[256];
    int t = threadIdx.x;
    int i = blockIdx.x * 256 + t;
    int c = (i < n) ? (int)(packed[i] >> 40) : 0;
    s[t] = c;
    __syncthreads();
#pragma unroll
    for (int off = 1; off < 256; off <<= 1) {
        int u = (t >= off) ? s[t - off] : 0;
        __syncthreads();
        s[t] += u;
        __syncthreads();
    }
    int excl = bsum[blockIdx.x] + s[t] - c;
    if (i < n) rowptr[i] = excl;
    if (i == n - 1) rowptr[n] = excl + c;
}

// Atomic-free scatter using precomputed ranks.
__global__ __launch_bounds__(256) void k_scatter(const int* __restrict__ src,
                                                 const int* __restrict__ dst,
                                                 const float* __restrict__ w,
                                                 const unsigned int* __restrict__ rank,
                                                 const float* __restrict__ dinv,
                                                 const int* __restrict__ rowptr,
                                                 int* __restrict__ col,
                                                 float* __restrict__ val, int E) {
    int e = blockIdx.x * 256 + threadIdx.x;
    if (e < E) {
        int s = src[e], d = dst[e];
        int p = rowptr[d] + (int)rank[e];
        col[p] = s;
        val[p] = dinv[s] * w[e] * dinv[d];
    }
}

// Y[r,:] = X[r,:] @ W (+bias). W is 128x128. 32 rows per block.
// LDS: W 64KB + X-tile 16KB = 80KB -> 2 blocks/CU. Safe in-place (X==Y):
// block stages its rows into LDS before any store.
__global__ __launch_bounds__(256) void k_gemm128(const float* __restrict__ X,
                                                 const float* __restrict__ W,
                                                 const float* __restrict__ bias,
                                                 float* __restrict__ Y,
                                                 int n, int add_bias) {
    __shared__ __align__(16) float Ws[128 * 128];
    __shared__ __align__(16) float Xs[32 * 128];
    int t = threadIdx.x;
    {   // stage W (row-major [k][c]) : 4096 float4
        const float4* W4 = (const float4*)W;
        float4* Ws4 = (float4*)Ws;
#pragma unroll
        for (int i = 0; i < 16; i++) Ws4[t + i * 256] = W4[t + i * 256];
    }
    int row0 = blockIdx.x * 32;
    {   // stage X tile: 32 rows x 128 (zeros past n)
        float4* Xs4 = (float4*)Xs;
        for (int i = t; i < 32 * 32; i += 256) {
            int r = i >> 5, c = i & 31;
            int gr = row0 + r;
            float4 v = make_float4(0.f, 0.f, 0.f, 0.f);
            if (gr < n) v = ((const float4*)(X + (size_t)gr * 128))[c];
            Xs4[i] = v;
        }
    }
    __syncthreads();

    int tx = t & 31;   // cols tx*4 .. tx*4+3
    int ty = t >> 5;   // rows ty*4 .. ty*4+3
    float acc[4][4];
#pragma unroll
    for (int r = 0; r < 4; r++)
#pragma unroll
        for (int c = 0; c < 4; c++) acc[r][c] = 0.f;

    const float4* Ws4 = (const float4*)Ws;
    const float4* Xs4 = (const float4*)Xs;
#pragma unroll 4
    for (int k = 0; k < 128; k += 4) {
        float4 w0 = Ws4[(k + 0) * 32 + tx];
        float4 w1 = Ws4[(k + 1) * 32 + tx];
        float4 w2 = Ws4[(k + 2) * 32 + tx];
        float4 w3 = Ws4[(k + 3) * 32 + tx];
#pragma unroll
        for (int r = 0; r < 4; r++) {
            float4 xv = Xs4[(ty * 4 + r) * 32 + (k >> 2)];
            acc[r][0] = fmaf(xv.x, w0.x, acc[r][0]);
            acc[r][0] = fmaf(xv.y, w1.x, acc[r][0]);
            acc[r][0] = fmaf(xv.z, w2.x, acc[r][0]);
            acc[r][0] = fmaf(xv.w, w3.x, acc[r][0]);
            acc[r][1] = fmaf(xv.x, w0.y, acc[r][1]);
            acc[r][1] = fmaf(xv.y, w1.y, acc[r][1]);
            acc[r][1] = fmaf(xv.z, w2.y, acc[r][1]);
            acc[r][1] = fmaf(xv.w, w3.y, acc[r][1]);
            acc[r][2] = fmaf(xv.x, w0.z, acc[r][2]);
            acc[r][2] = fmaf(xv.y, w1.z, acc[r][2]);
            acc[r][2] = fmaf(xv.z, w2.z, acc[r][2]);
            acc[r][2] = fmaf(xv.w, w3.z, acc[r][2]);
            acc[r][3] = fmaf(xv.x, w0.w, acc[r][3]);
            acc[r][3] = fmaf(xv.y, w1.w, acc[r][3]);
            acc[r][3] = fmaf(xv.z, w2.w, acc[r][3]);
            acc[r][3] = fmaf(xv.w, w3.w, acc[r][3]);
        }
    }

    float4 bv = make_float4(0.f, 0.f, 0.f, 0.f);
    if (add_bias) bv = ((const float4*)bias)[tx];
#pragma unroll
    for (int r = 0; r < 4; r++) {
        int gr = row0 + ty * 4 + r;
        if (gr < n) {
            float4 o = make_float4(acc[r][0] + bv.x, acc[r][1] + bv.y,
                                   acc[r][2] + bv.z, acc[r][3] + bv.w);
            ((float4*)(Y + (size_t)gr * 128))[tx] = o;
        }
    }
}

// One wave per node; lane holds 2 features (float2 -> 512B coalesced rows).
__global__ __launch_bounds__(256) void k_agg(const float* __restrict__ H,
                                             const int* __restrict__ rowptr,
                                             const int* __restrict__ col,
                                             const float* __restrict__ val,
                                             const float* __restrict__ dinv,
                                             const float* __restrict__ bias,
                                             float* __restrict__ out,
                                             int n, int do_relu) {
    int wid = (blockIdx.x * 256 + threadIdx.x) >> 6;
    int lane = threadIdx.x & 63;
    if (wid >= n) return;
    int i = __builtin_amdgcn_readfirstlane(wid);  // wave-uniform -> scalar loads
    float di = dinv[i];
    float2 h0 = ((const float2*)(H + (size_t)i * 128))[lane];
    float w0 = di * di;
    float ax = w0 * h0.x, ay = w0 * h0.y;
    int e0 = rowptr[i], e1 = rowptr[i + 1];
    for (int e = e0; e < e1; e++) {
        int s = col[e];
        float v = val[e];
        float2 h = ((const float2*)(H + (size_t)s * 128))[lane];
        ax = fmaf(v, h.x, ax);
        ay = fmaf(v, h.y, ay);
    }
    float2 b = ((const float2*)bias)[lane];
    ax += b.x; ay += b.y;
    if (do_relu) { ax = fmaxf(ax, 0.f); ay = fmaxf(ay, 0.f); }
    ((float2*)(out + (size_t)i * 128))[lane] = make_float2(ax, ay);
}

extern "C" void kernel_launch(void* const* d_in, const int* in_sizes, int n_in,
                              void* d_out, int out_size, void* d_ws, size_t ws_size,
                              hipStream_t stream) {
    const float* x   = (const float*)d_in[0];
    const float* ew  = (const float*)d_in[1];
    const float* W1  = (const float*)d_in[2];
    const float* b1  = (const float*)d_in[3];
    const float* W2  = (const float*)d_in[4];
    const float* b2  = (const float*)d_in[5];
    const float* Wfc = (const float*)d_in[6];
    const float* bfc = (const float*)d_in[7];
    const int* eidx  = (const int*)d_in[8];

    const int E = in_sizes[1];
    const int N = in_sizes[0] / 128;
    const int* src = eidx;       // edge_index row 0
    const int* dst = eidx + E;   // edge_index row 1

    char* ws = (char*)d_ws;
    size_t off = 0;
    auto alloc = [&](size_t bytes) -> void* {
        void* p = ws + off;
        off = (off + bytes + 255) & ~(size_t)255;
        return p;
    };
    int nb = (N + 255) / 256;    // 196 for N=50000 (must be <= 256)
    int eb = (E + 255) / 256;
    int gb = (N + 31) / 32;
    int ab = (N * 64 + 255) / 256;

    u64*   packed = (u64*)alloc((size_t)N * 8);
    float* dinv   = (float*)alloc((size_t)N * 4);
    int*   rowptr = (int*)alloc((size_t)(N + 1) * 4);
    int*   bsum   = (int*)alloc((size_t)nb * 4);
    unsigned int* rank = (unsigned int*)alloc((size_t)E * 4);
    int*   col    = (int*)alloc((size_t)E * 4);
    float* val    = (float*)alloc((size_t)E * 4);
    float* buf0   = (float*)alloc((size_t)N * 128 * 4);
    float* out    = (float*)d_out;

    // Graph prep (re-done every launch; no state caching)
    k_init<<<nb, 256, 0, stream>>>(packed, N);
    k_edge_deg<<<eb, 256, 0, stream>>>(dst, ew, packed, rank, E);
    k_part<<<nb, 256, 0, stream>>>(packed, dinv, bsum, N);
    k_scan_bsums<<<1, 256, 0, stream>>>(bsum, nb);
    k_rowptr<<<nb, 256, 0, stream>>>(packed, bsum, rowptr, N);
    k_scatter<<<eb, 256, 0, stream>>>(src, dst, ew, rank, dinv, rowptr, col, val, E);

    // Layer 1
    k_gemm128<<<gb, 256, 0, stream>>>(x, W1, nullptr, buf0, N, 0);
    k_agg<<<ab, 256, 0, stream>>>(buf0, rowptr, col, val, dinv, b1, out, N, 1);
    // Layer 2
    k_gemm128<<<gb, 256, 0, stream>>>(out, W2, nullptr, buf0, N, 0);
    k_agg<<<ab, 256, 0, stream>>>(buf0, rowptr, col, val, dinv, b2, out, N, 1);
    // FC (in-place on d_out: block stages its rows to LDS before storing)
    k_gemm128<<<gb, 256, 0, stream>>>(out, Wfc, bfc, out, N, 1);
}

// Round 4
// 373.273 us; speedup vs baseline: 1.4823x; 1.0405x over previous
//
#include <hip/hip_runtime.h>
#include <hip/hip_fp16.h>

// ---------------------------------------------------------------------------
// GCN: h1 = relu(Agg(x@W1)+b1); h2 = relu(Agg(h1@W2)+b2); out = h2@Wfc+bfc
// Agg(h)[i] = sum_{e: dst[e]==i} dinv[src]*w*dinv[i] * h[src] + dinv[i]^2*h[i]
// CSR-by-dst built per launch.
// R1: multi-block scan (553->452us).
// R2: 3 atomics/edge -> 1 packed u64 atomic/edge (452->388us).
// R3: intermediates in fp16. k_agg was traffic-bound on the L2-miss path
// (FETCH 192MB vs 25.6MB matrix; random gather defeats per-XCD 4MB L2s).
// fp16 halves bytes/row (256B); all FMA stays fp32 (bf16 would risk the
// 1e-2 absmax budget, fp16 adds only ~5e-4 relative per rounding).
// ---------------------------------------------------------------------------

typedef unsigned long long u64;

struct __align__(8) Half4 { __half2 lo, hi; };

__global__ __launch_bounds__(256) void k_init(u64* packed, int n) {
    int i = blockIdx.x * 256 + threadIdx.x;
    if (i < n) packed[i] = 0ULL;
}

// One u64 atomic per edge: count in bits [40,64), fixed-point weight sum
// (2^24 scale) in bits [0,40). Old value >> 40 = this edge's rank in row.
__global__ __launch_bounds__(256) void k_edge_deg(const int* __restrict__ dst,
                                                  const float* __restrict__ w,
                                                  u64* __restrict__ packed,
                                                  unsigned int* __restrict__ rank, int E) {
    int e = blockIdx.x * 256 + threadIdx.x;
    if (e < E) {
        int d = dst[e];
        u64 add = (1ULL << 40) | (u64)(w[e] * 16777216.0f);
        u64 old = atomicAdd(&packed[d], add);
        rank[e] = (unsigned int)(old >> 40);
    }
}

// Phase 1: per-block sum of counts -> bsum[block]; fused dinv = rsqrt(deg).
__global__ __launch_bounds__(256) void k_part(const u64* __restrict__ packed,
                                              float* __restrict__ dinv,
                                              int* __restrict__ bsum, int n) {
    __shared__ int red[256];
    int t = threadIdx.x;
    int i = blockIdx.x * 256 + t;
    int c = 0;
    if (i < n) {
        u64 p = packed[i];
        c = (int)(p >> 40);
        float degsum = (float)(p & ((1ULL << 40) - 1)) * (1.0f / 16777216.0f);
        dinv[i] = rsqrtf(1.0f + degsum);   // self-loop weight 1
    }
    red[t] = c;
    __syncthreads();
#pragma unroll
    for (int off = 128; off > 0; off >>= 1) {
        if (t < off) red[t] += red[t + off];
        __syncthreads();
    }
    if (t == 0) bsum[blockIdx.x] = red[0];
}

// Phase 2: single block exclusive-scans bsum (nb <= 256 for N=50000).
__global__ __launch_bounds__(256) void k_scan_bsums(int* bsum, int nb) {
    __shared__ int s[256];
    int t = threadIdx.x;
    s[t] = (t < nb) ? bsum[t] : 0;
    __syncthreads();
#pragma unroll
    for (int off = 1; off < 256; off <<= 1) {
        int u = (t >= off) ? s[t - off] : 0;
        __syncthreads();
        s[t] += u;
        __syncthreads();
    }
    if (t < nb) bsum[t] = (t == 0) ? 0 : s[t - 1];
}

// Phase 3: block-local inclusive scan + bsum offset -> rowptr.
__global__ __launch_bounds__(256) void k_rowptr(const u64* __restrict__ packed,
                                                const int* __restrict__ bsum,
                                                int* __restrict__ rowptr, int n) {
    __shared__ int s[256];
    int t = threadIdx.x;
    int i = blockIdx.x * 256 + t;
    int c = (i < n) ? (int)(packed[i] >> 40) : 0;
    s[t] = c;
    __syncthreads();
#pragma unroll
    for (int off = 1; off < 256; off <<= 1) {
        int u = (t >= off) ? s[t - off] : 0;
        __syncthreads();
        s[t] += u;
        __syncthreads();
    }
    int excl = bsum[blockIdx.x] + s[t] - c;
    if (i < n) rowptr[i] = excl;
    if (i == n - 1) rowptr[n] = excl + c;
}

// Atomic-free scatter using precomputed ranks.
__global__ __launch_bounds__(256) void k_scatter(const int* __restrict__ src,
                                                 const int* __restrict__ dst,
                                                 const float* __restrict__ w,
                                                 const unsigned int* __restrict__ rank,
                                                 const float* __restrict__ dinv,
                                                 const int* __restrict__ rowptr,
                                                 int* __restrict__ col,
                                                 float* __restrict__ val, int E) {
    int e = blockIdx.x * 256 + threadIdx.x;
    if (e < E) {
        int s = src[e], d = dst[e];
        int p = rowptr[d] + (int)rank[e];
        col[p] = s;
        val[p] = dinv[s] * w[e] * dinv[d];
    }
}

// Y[r,:] = X[r,:] @ W (+bias). W 128x128 fp32. 32 rows/block.
// IN_HALF/OUT_HALF select fp16 storage for X/Y; FMA math is fp32.
// LDS: W 64KB + X-tile 16KB = 80KB -> 2 blocks/CU.
template <bool IN_HALF, bool OUT_HALF>
__global__ __launch_bounds__(256) void k_gemm128(const void* __restrict__ Xv,
                                                 const float* __restrict__ W,
                                                 const float* __restrict__ bias,
                                                 void* __restrict__ Yv,
                                                 int n, int add_bias) {
    __shared__ __align__(16) float Ws[128 * 128];
    __shared__ __align__(16) float Xs[32 * 128];
    int t = threadIdx.x;
    {   // stage W (row-major [k][c]) : 4096 float4
        const float4* W4 = (const float4*)W;
        float4* Ws4 = (float4*)Ws;
#pragma unroll
        for (int i = 0; i < 16; i++) Ws4[t + i * 256] = W4[t + i * 256];
    }
    int row0 = blockIdx.x * 32;
    if (!IN_HALF) {   // stage X tile fp32: 32 rows x 128
        const float* X = (const float*)Xv;
        float4* Xs4 = (float4*)Xs;
        for (int i = t; i < 32 * 32; i += 256) {
            int r = i >> 5, c = i & 31;
            int gr = row0 + r;
            float4 v = make_float4(0.f, 0.f, 0.f, 0.f);
            if (gr < n) v = ((const float4*)(X + (size_t)gr * 128))[c];
            Xs4[i] = v;
        }
    } else {          // stage X tile fp16 -> convert to fp32 in LDS
        const __half* X = (const __half*)Xv;
        for (int i = t; i < 32 * 64; i += 256) {   // 2048 half2 chunks
            int r = i >> 6, c2 = i & 63;
            int gr = row0 + r;
            float2 f = make_float2(0.f, 0.f);
            if (gr < n) f = __half22float2(((const __half2*)(X + (size_t)gr * 128))[c2]);
            Xs[r * 128 + c2 * 2] = f.x;
            Xs[r * 128 + c2 * 2 + 1] = f.y;
        }
    }
    __syncthreads();

    int tx = t & 31;   // cols tx*4 .. tx*4+3
    int ty = t >> 5;   // rows ty*4 .. ty*4+3
    float acc[4][4];
#pragma unroll
    for (int r = 0; r < 4; r++)
#pragma unroll
        for (int c = 0; c < 4; c++) acc[r][c] = 0.f;

    const float4* Ws4 = (const float4*)Ws;
    const float4* Xs4 = (const float4*)Xs;
#pragma unroll 4
    for (int k = 0; k < 128; k += 4) {
        float4 w0 = Ws4[(k + 0) * 32 + tx];
        float4 w1 = Ws4[(k + 1) * 32 + tx];
        float4 w2 = Ws4[(k + 2) * 32 + tx];
        float4 w3 = Ws4[(k + 3) * 32 + tx];
#pragma unroll
        for (int r = 0; r < 4; r++) {
            float4 xv = Xs4[(ty * 4 + r) * 32 + (k >> 2)];
            acc[r][0] = fmaf(xv.x, w0.x, acc[r][0]);
            acc[r][0] = fmaf(xv.y, w1.x, acc[r][0]);
            acc[r][0] = fmaf(xv.z, w2.x, acc[r][0]);
            acc[r][0] = fmaf(xv.w, w3.x, acc[r][0]);
            acc[r][1] = fmaf(xv.x, w0.y, acc[r][1]);
            acc[r][1] = fmaf(xv.y, w1.y, acc[r][1]);
            acc[r][1] = fmaf(xv.z, w2.y, acc[r][1]);
            acc[r][1] = fmaf(xv.w, w3.y, acc[r][1]);
            acc[r][2] = fmaf(xv.x, w0.z, acc[r][2]);
            acc[r][2] = fmaf(xv.y, w1.z, acc[r][2]);
            acc[r][2] = fmaf(xv.z, w2.z, acc[r][2]);
            acc[r][2] = fmaf(xv.w, w3.z, acc[r][2]);
            acc[r][3] = fmaf(xv.x, w0.w, acc[r][3]);
            acc[r][3] = fmaf(xv.y, w1.w, acc[r][3]);
            acc[r][3] = fmaf(xv.z, w2.w, acc[r][3]);
            acc[r][3] = fmaf(xv.w, w3.w, acc[r][3]);
        }
    }

    float4 bv = make_float4(0.f, 0.f, 0.f, 0.f);
    if (add_bias) bv = ((const float4*)bias)[tx];
#pragma unroll
    for (int r = 0; r < 4; r++) {
        int gr = row0 + ty * 4 + r;
        if (gr < n) {
            float4 o = make_float4(acc[r][0] + bv.x, acc[r][1] + bv.y,
                                   acc[r][2] + bv.z, acc[r][3] + bv.w);
            if (!OUT_HALF) {
                ((float4*)((float*)Yv + (size_t)gr * 128))[tx] = o;
            } else {
                Half4 h;
                h.lo = __floats2half2_rn(o.x, o.y);
                h.hi = __floats2half2_rn(o.z, o.w);
                ((Half4*)((__half*)Yv + (size_t)gr * 128))[tx] = h;
            }
        }
    }
}

// One wave per node; lane holds 2 features as half2 (256B coalesced rows).
// Accumulate fp32, store fp16. ReLU always on (both agg layers have it).
__global__ __launch_bounds__(256) void k_agg(const __half* __restrict__ H,
                                             const int* __restrict__ rowptr,
                                             const int* __restrict__ col,
                                             const float* __restrict__ val,
                                             const float* __restrict__ dinv,
                                             const float* __restrict__ bias,
                                             __half* __restrict__ out, int n) {
    int wid = (blockIdx.x * 256 + threadIdx.x) >> 6;
    int lane = threadIdx.x & 63;
    if (wid >= n) return;
    int i = __builtin_amdgcn_readfirstlane(wid);  // wave-uniform -> scalar loads
    float di = dinv[i];
    float2 h0 = __half22float2(((const __half2*)(H + (size_t)i * 128))[lane]);
    float w0 = di * di;
    float ax = w0 * h0.x, ay = w0 * h0.y;
    int e0 = rowptr[i], e1 = rowptr[i + 1];
    for (int e = e0; e < e1; e++) {
        int s = col[e];
        float v = val[e];
        float2 h = __half22float2(((const __half2*)(H + (size_t)s * 128))[lane]);
        ax = fmaf(v, h.x, ax);
        ay = fmaf(v, h.y, ay);
    }
    float2 b = ((const float2*)bias)[lane];
    ax = fmaxf(ax + b.x, 0.f);
    ay = fmaxf(ay + b.y, 0.f);
    ((__half2*)(out + (size_t)i * 128))[lane] = __floats2half2_rn(ax, ay);
}

extern "C" void kernel_launch(void* const* d_in, const int* in_sizes, int n_in,
                              void* d_out, int out_size, void* d_ws, size_t ws_size,
                              hipStream_t stream) {
    const float* x   = (const float*)d_in[0];
    const float* ew  = (const float*)d_in[1];
    const float* W1  = (const float*)d_in[2];
    const float* b1  = (const float*)d_in[3];
    const float* W2  = (const float*)d_in[4];
    const float* b2  = (const float*)d_in[5];
    const float* Wfc = (const float*)d_in[6];
    const float* bfc = (const float*)d_in[7];
    const int* eidx  = (const int*)d_in[8];

    const int E = in_sizes[1];
    const int N = in_sizes[0] / 128;
    const int* src = eidx;       // edge_index row 0
    const int* dst = eidx + E;   // edge_index row 1

    char* ws = (char*)d_ws;
    size_t off = 0;
    auto alloc = [&](size_t bytes) -> void* {
        void* p = ws + off;
        off = (off + bytes + 255) & ~(size_t)255;
        return p;
    };
    int nb = (N + 255) / 256;    // 196 for N=50000 (must be <= 256)
    int eb = (E + 255) / 256;
    int gb = (N + 31) / 32;
    int ab = (N * 64 + 255) / 256;

    u64*   packed = (u64*)alloc((size_t)N * 8);
    float* dinv   = (float*)alloc((size_t)N * 4);
    int*   rowptr = (int*)alloc((size_t)(N + 1) * 4);
    int*   bsum   = (int*)alloc((size_t)nb * 4);
    unsigned int* rank = (unsigned int*)alloc((size_t)E * 4);
    int*   col    = (int*)alloc((size_t)E * 4);
    float* val    = (float*)alloc((size_t)E * 4);
    __half* bufH  = (__half*)alloc((size_t)N * 128 * 2);  // gemm output
    __half* bufA  = (__half*)alloc((size_t)N * 128 * 2);  // agg output
    float* out    = (float*)d_out;

    // Graph prep (re-done every launch; no state caching)
    k_init<<<nb, 256, 0, stream>>>(packed, N);
    k_edge_deg<<<eb, 256, 0, stream>>>(dst, ew, packed, rank, E);
    k_part<<<nb, 256, 0, stream>>>(packed, dinv, bsum, N);
    k_scan_bsums<<<1, 256, 0, stream>>>(bsum, nb);
    k_rowptr<<<nb, 256, 0, stream>>>(packed, bsum, rowptr, N);
    k_scatter<<<eb, 256, 0, stream>>>(src, dst, ew, rank, dinv, rowptr, col, val, E);

    // Layer 1: x(fp32) @ W1 -> fp16; agg fp16 -> fp16
    k_gemm128<false, true><<<gb, 256, 0, stream>>>(x, W1, nullptr, bufH, N, 0);
    k_agg<<<ab, 256, 0, stream>>>(bufH, rowptr, col, val, dinv, b1, bufA, N);
    // Layer 2 (bufH reused: gemm reads only its own staged rows from bufA)
    k_gemm128<true, true><<<gb, 256, 0, stream>>>(bufA, W2, nullptr, bufH, N, 0);
    k_agg<<<ab, 256, 0, stream>>>(bufH, rowptr, col, val, dinv, b2, bufA, N);
    // FC: fp16 in, fp32 out to d_out
    k_gemm128<true, false><<<gb, 256, 0, stream>>>(bufA, Wfc, bfc, d_out, N, 1);
}

// Round 5
// 331.886 us; speedup vs baseline: 1.6672x; 1.1247x over previous
//
#include <hip/hip_runtime.h>
#include <hip/hip_fp16.h>

// ---------------------------------------------------------------------------
// GCN: h1 = relu(Agg(x@W1)+b1); h2 = relu(Agg(h1@W2)+b2); out = h2@Wfc+bfc
// Agg(h)[i] = sum_{e: dst[e]==i} dinv[src]*w*dinv[i] * h[src] + dinv[i]^2*h[i]
// CSR-by-dst built per launch.
// R1: multi-block scan (553->452us).
// R2: 3 atomics/edge -> 1 packed u64 atomic/edge (452->388us).
// R3: fp16 intermediates halve gather bytes (388->373; FETCH 192->88MB).
// R4: k_agg went latency-bound (HBM 23%, VALU 11%) - serial col[e]->gather
// chain. Fix: wave coop-loads 64 col/val at once (1 coalesced load), then
// __shfl-broadcast + batches of 8 independent gathers before the fmas, so
// 8 loads are in flight per latency window instead of 1.
// ---------------------------------------------------------------------------

typedef unsigned long long u64;

struct __align__(8) Half4 { __half2 lo, hi; };

__global__ __launch_bounds__(256) void k_init(u64* packed, int n) {
    int i = blockIdx.x * 256 + threadIdx.x;
    if (i < n) packed[i] = 0ULL;
}

// One u64 atomic per edge: count in bits [40,64), fixed-point weight sum
// (2^24 scale) in bits [0,40). Old value >> 40 = this edge's rank in row.
__global__ __launch_bounds__(256) void k_edge_deg(const int* __restrict__ dst,
                                                  const float* __restrict__ w,
                                                  u64* __restrict__ packed,
                                                  unsigned int* __restrict__ rank, int E) {
    int e = blockIdx.x * 256 + threadIdx.x;
    if (e < E) {
        int d = dst[e];
        u64 add = (1ULL << 40) | (u64)(w[e] * 16777216.0f);
        u64 old = atomicAdd(&packed[d], add);
        rank[e] = (unsigned int)(old >> 40);
    }
}

// Phase 1: per-block sum of counts -> bsum[block]; fused dinv = rsqrt(deg).
__global__ __launch_bounds__(256) void k_part(const u64* __restrict__ packed,
                                              float* __restrict__ dinv,
                                              int* __restrict__ bsum, int n) {
    __shared__ int red[256];
    int t = threadIdx.x;
    int i = blockIdx.x * 256 + t;
    int c = 0;
    if (i < n) {
        u64 p = packed[i];
        c = (int)(p >> 40);
        float degsum = (float)(p & ((1ULL << 40) - 1)) * (1.0f / 16777216.0f);
        dinv[i] = rsqrtf(1.0f + degsum);   // self-loop weight 1
    }
    red[t] = c;
    __syncthreads();
#pragma unroll
    for (int off = 128; off > 0; off >>= 1) {
        if (t < off) red[t] += red[t + off];
        __syncthreads();
    }
    if (t == 0) bsum[blockIdx.x] = red[0];
}

// Phase 2: single block exclusive-scans bsum (nb <= 256 for N=50000).
__global__ __launch_bounds__(256) void k_scan_bsums(int* bsum, int nb) {
    __shared__ int s[256];
    int t = threadIdx.x;
    s[t] = (t < nb) ? bsum[t] : 0;
    __syncthreads();
#pragma unroll
    for (int off = 1; off < 256; off <<= 1) {
        int u = (t >= off) ? s[t - off] : 0;
        __syncthreads();
        s[t] += u;
        __syncthreads();
    }
    if (t < nb) bsum[t] = (t == 0) ? 0 : s[t - 1];
}

// Phase 3: block-local inclusive scan + bsum offset -> rowptr.
__global__ __launch_bounds__(256) void k_rowptr(const u64* __restrict__ packed,
                                                const int* __restrict__ bsum,
                                                int* __restrict__ rowptr, int n) {
    __shared__ int s[256];
    int t = threadIdx.x;
    int i = blockIdx.x * 256 + t;
    int c = (i < n) ? (int)(packed[i] >> 40) : 0;
    s[t] = c;
    __syncthreads();
#pragma unroll
    for (int off = 1; off < 256; off <<= 1) {
        int u = (t >= off) ? s[t - off] : 0;
        __syncthreads();
        s[t] += u;
        __syncthreads();
    }
    int excl = bsum[blockIdx.x] + s[t] - c;
    if (i < n) rowptr[i] = excl;
    if (i == n - 1) rowptr[n] = excl + c;
}

// Atomic-free scatter using precomputed ranks.
__global__ __launch_bounds__(256) void k_scatter(const int* __restrict__ src,
                                                 const int* __restrict__ dst,
                                                 const float* __restrict__ w,
                                                 const unsigned int* __restrict__ rank,
                                                 const float* __restrict__ dinv,
                                                 const int* __restrict__ rowptr,
                                                 int* __restrict__ col,
                                                 float* __restrict__ val, int E) {
    int e = blockIdx.x * 256 + threadIdx.x;
    if (e < E) {
        int s = src[e], d = dst[e];
        int p = rowptr[d] + (int)rank[e];
        col[p] = s;
        val[p] = dinv[s] * w[e] * dinv[d];
    }
}

// Y[r,:] = X[r,:] @ W (+bias). W 128x128 fp32. 32 rows/block.
// IN_HALF/OUT_HALF select fp16 storage for X/Y; FMA math is fp32.
// LDS: W 64KB + X-tile 16KB = 80KB -> 2 blocks/CU.
template <bool IN_HALF, bool OUT_HALF>
__global__ __launch_bounds__(256) void k_gemm128(const void* __restrict__ Xv,
                                                 const float* __restrict__ W,
                                                 const float* __restrict__ bias,
                                                 void* __restrict__ Yv,
                                                 int n, int add_bias) {
    __shared__ __align__(16) float Ws[128 * 128];
    __shared__ __align__(16) float Xs[32 * 128];
    int t = threadIdx.x;
    {   // stage W (row-major [k][c]) : 4096 float4
        const float4* W4 = (const float4*)W;
        float4* Ws4 = (float4*)Ws;
#pragma unroll
        for (int i = 0; i < 16; i++) Ws4[t + i * 256] = W4[t + i * 256];
    }
    int row0 = blockIdx.x * 32;
    if (!IN_HALF) {   // stage X tile fp32: 32 rows x 128
        const float* X = (const float*)Xv;
        float4* Xs4 = (float4*)Xs;
        for (int i = t; i < 32 * 32; i += 256) {
            int r = i >> 5, c = i & 31;
            int gr = row0 + r;
            float4 v = make_float4(0.f, 0.f, 0.f, 0.f);
            if (gr < n) v = ((const float4*)(X + (size_t)gr * 128))[c];
            Xs4[i] = v;
        }
    } else {          // stage X tile fp16 -> convert to fp32 in LDS
        const __half* X = (const __half*)Xv;
        for (int i = t; i < 32 * 64; i += 256) {   // 2048 half2 chunks
            int r = i >> 6, c2 = i & 63;
            int gr = row0 + r;
            float2 f = make_float2(0.f, 0.f);
            if (gr < n) f = __half22float2(((const __half2*)(X + (size_t)gr * 128))[c2]);
            Xs[r * 128 + c2 * 2] = f.x;
            Xs[r * 128 + c2 * 2 + 1] = f.y;
        }
    }
    __syncthreads();

    int tx = t & 31;   // cols tx*4 .. tx*4+3
    int ty = t >> 5;   // rows ty*4 .. ty*4+3
    float acc[4][4];
#pragma unroll
    for (int r = 0; r < 4; r++)
#pragma unroll
        for (int c = 0; c < 4; c++) acc[r][c] = 0.f;

    const float4* Ws4 = (const float4*)Ws;
    const float4* Xs4 = (const float4*)Xs;
#pragma unroll 4
    for (int k = 0; k < 128; k += 4) {
        float4 w0 = Ws4[(k + 0) * 32 + tx];
        float4 w1 = Ws4[(k + 1) * 32 + tx];
        float4 w2 = Ws4[(k + 2) * 32 + tx];
        float4 w3 = Ws4[(k + 3) * 32 + tx];
#pragma unroll
        for (int r = 0; r < 4; r++) {
            float4 xv = Xs4[(ty * 4 + r) * 32 + (k >> 2)];
            acc[r][0] = fmaf(xv.x, w0.x, acc[r][0]);
            acc[r][0] = fmaf(xv.y, w1.x, acc[r][0]);
            acc[r][0] = fmaf(xv.z, w2.x, acc[r][0]);
            acc[r][0] = fmaf(xv.w, w3.x, acc[r][0]);
            acc[r][1] = fmaf(xv.x, w0.y, acc[r][1]);
            acc[r][1] = fmaf(xv.y, w1.y, acc[r][1]);
            acc[r][1] = fmaf(xv.z, w2.y, acc[r][1]);
            acc[r][1] = fmaf(xv.w, w3.y, acc[r][1]);
            acc[r][2] = fmaf(xv.x, w0.z, acc[r][2]);
            acc[r][2] = fmaf(xv.y, w1.z, acc[r][2]);
            acc[r][2] = fmaf(xv.z, w2.z, acc[r][2]);
            acc[r][2] = fmaf(xv.w, w3.z, acc[r][2]);
            acc[r][3] = fmaf(xv.x, w0.w, acc[r][3]);
            acc[r][3] = fmaf(xv.y, w1.w, acc[r][3]);
            acc[r][3] = fmaf(xv.z, w2.w, acc[r][3]);
            acc[r][3] = fmaf(xv.w, w3.w, acc[r][3]);
        }
    }

    float4 bv = make_float4(0.f, 0.f, 0.f, 0.f);
    if (add_bias) bv = ((const float4*)bias)[tx];
#pragma unroll
    for (int r = 0; r < 4; r++) {
        int gr = row0 + ty * 4 + r;
        if (gr < n) {
            float4 o = make_float4(acc[r][0] + bv.x, acc[r][1] + bv.y,
                                   acc[r][2] + bv.z, acc[r][3] + bv.w);
            if (!OUT_HALF) {
                ((float4*)((float*)Yv + (size_t)gr * 128))[tx] = o;
            } else {
                Half4 h;
                h.lo = __floats2half2_rn(o.x, o.y);
                h.hi = __floats2half2_rn(o.z, o.w);
                ((Half4*)((__half*)Yv + (size_t)gr * 128))[tx] = h;
            }
        }
    }
}

// One wave per node; lane holds 2 features as half2 (256B coalesced rows).
// R4: coop-load up to 64 col/val per row in one coalesced load, broadcast
// via __shfl, and issue gathers in unrolled batches of 8 so 8 loads are in
// flight before the first fma waits. Accumulate fp32, store fp16 + ReLU.
__global__ __launch_bounds__(256) void k_agg(const __half* __restrict__ H,
                                             const int* __restrict__ rowptr,
                                             const int* __restrict__ col,
                                             const float* __restrict__ val,
                                             const float* __restrict__ dinv,
                                             const float* __restrict__ bias,
                                             __half* __restrict__ out, int n) {
    int wid = (blockIdx.x * 256 + threadIdx.x) >> 6;
    int lane = threadIdx.x & 63;
    if (wid >= n) return;
    int i = __builtin_amdgcn_readfirstlane(wid);  // wave-uniform -> scalar loads
    float di = dinv[i];
    float2 h0 = __half22float2(((const __half2*)(H + (size_t)i * 128))[lane]);
    float w0 = di * di;
    float ax = w0 * h0.x, ay = w0 * h0.y;
    int e0 = rowptr[i], e1 = rowptr[i + 1];

    for (int base = e0; base < e1; base += 64) {
        int cnt = min(64, e1 - base);
        int myc = 0; float myv = 0.f;
        if (lane < cnt) { myc = col[base + lane]; myv = val[base + lane]; }
        int j = 0;
        for (; j + 8 <= cnt; j += 8) {
            float2 h[8];
            float v[8];
#pragma unroll
            for (int u = 0; u < 8; u++) {
                int s = __shfl(myc, j + u);
                v[u] = __shfl(myv, j + u);
                h[u] = __half22float2(((const __half2*)(H + (size_t)s * 128))[lane]);
            }
#pragma unroll
            for (int u = 0; u < 8; u++) {
                ax = fmaf(v[u], h[u].x, ax);
                ay = fmaf(v[u], h[u].y, ay);
            }
        }
        for (; j < cnt; j++) {
            int s = __shfl(myc, j);
            float v = __shfl(myv, j);
            float2 h = __half22float2(((const __half2*)(H + (size_t)s * 128))[lane]);
            ax = fmaf(v, h.x, ax);
            ay = fmaf(v, h.y, ay);
        }
    }
    float2 b = ((const float2*)bias)[lane];
    ax = fmaxf(ax + b.x, 0.f);
    ay = fmaxf(ay + b.y, 0.f);
    ((__half2*)(out + (size_t)i * 128))[lane] = __floats2half2_rn(ax, ay);
}

extern "C" void kernel_launch(void* const* d_in, const int* in_sizes, int n_in,
                              void* d_out, int out_size, void* d_ws, size_t ws_size,
                              hipStream_t stream) {
    const float* x   = (const float*)d_in[0];
    const float* ew  = (const float*)d_in[1];
    const float* W1  = (const float*)d_in[2];
    const float* b1  = (const float*)d_in[3];
    const float* W2  = (const float*)d_in[4];
    const float* b2  = (const float*)d_in[5];
    const float* Wfc = (const float*)d_in[6];
    const float* bfc = (const float*)d_in[7];
    const int* eidx  = (const int*)d_in[8];

    const int E = in_sizes[1];
    const int N = in_sizes[0] / 128;
    const int* src = eidx;       // edge_index row 0
    const int* dst = eidx + E;   // edge_index row 1

    char* ws = (char*)d_ws;
    size_t off = 0;
    auto alloc = [&](size_t bytes) -> void* {
        void* p = ws + off;
        off = (off + bytes + 255) & ~(size_t)255;
        return p;
    };
    int nb = (N + 255) / 256;    // 196 for N=50000 (must be <= 256)
    int eb = (E + 255) / 256;
    int gb = (N + 31) / 32;
    int ab = (N * 64 + 255) / 256;

    u64*   packed = (u64*)alloc((size_t)N * 8);
    float* dinv   = (float*)alloc((size_t)N * 4);
    int*   rowptr = (int*)alloc((size_t)(N + 1) * 4);
    int*   bsum   = (int*)alloc((size_t)nb * 4);
    unsigned int* rank = (unsigned int*)alloc((size_t)E * 4);
    int*   col    = (int*)alloc((size_t)E * 4);
    float* val    = (float*)alloc((size_t)E * 4);
    __half* bufH  = (__half*)alloc((size_t)N * 128 * 2);  // gemm output
    __half* bufA  = (__half*)alloc((size_t)N * 128 * 2);  // agg output
    float* out    = (float*)d_out;

    // Graph prep (re-done every launch; no state caching)
    k_init<<<nb, 256, 0, stream>>>(packed, N);
    k_edge_deg<<<eb, 256, 0, stream>>>(dst, ew, packed, rank, E);
    k_part<<<nb, 256, 0, stream>>>(packed, dinv, bsum, N);
    k_scan_bsums<<<1, 256, 0, stream>>>(bsum, nb);
    k_rowptr<<<nb, 256, 0, stream>>>(packed, bsum, rowptr, N);
    k_scatter<<<eb, 256, 0, stream>>>(src, dst, ew, rank, dinv, rowptr, col, val, E);

    // Layer 1: x(fp32) @ W1 -> fp16; agg fp16 -> fp16
    k_gemm128<false, true><<<gb, 256, 0, stream>>>(x, W1, nullptr, bufH, N, 0);
    k_agg<<<ab, 256, 0, stream>>>(bufH, rowptr, col, val, dinv, b1, bufA, N);
    // Layer 2 (bufH reused: gemm reads only its own staged rows from bufA)
    k_gemm128<true, true><<<gb, 256, 0, stream>>>(bufA, W2, nullptr, bufH, N, 0);
    k_agg<<<ab, 256, 0, stream>>>(bufH, rowptr, col, val, dinv, b2, bufA, N);
    // FC: fp16 in, fp32 out to d_out
    k_gemm128<true, false><<<gb, 256, 0, stream>>>(bufA, Wfc, bfc, d_out, N, 1);
}

// Round 6
// 259.023 us; speedup vs baseline: 2.1361x; 1.2813x over previous
//
#include <hip/hip_runtime.h>
#include <hip/hip_fp16.h>

// ---------------------------------------------------------------------------
// GCN: h1 = relu(Agg(x@W1)+b1); h2 = relu(Agg(h1@W2)+b2); out = h2@Wfc+bfc
// Agg(h)[i] = sum_{e: dst[e]==i} dinv[src]*w*dinv[i] * h[src] + dinv[i]^2*h[i]
// CSR-by-dst built per launch.
// R1: multi-block scan (553->452us).
// R2: 3 atomics/edge -> 1 packed u64 atomic/edge (452->388us).
// R3: fp16 intermediates halve gather bytes (388->373; FETCH 192->88MB).
// R4: k_agg batched gathers, 8 loads in flight (373->332us).
// R5: fp32 vector GEMM (43.6us ea, VALUBusy 31%, 37TF) -> MFMA 16x16x32_f16
// with fp32 accumulate. Weights pre-transposed to fp16 Wt[n][k]; LDS-staged
// with +8-half pad (2-way bank alias = free). 64 rows/block, 4 blocks/CU.
// ---------------------------------------------------------------------------

typedef unsigned long long u64;
typedef _Float16 f16x8 __attribute__((ext_vector_type(8)));
typedef float f32x4 __attribute__((ext_vector_type(4)));

__global__ __launch_bounds__(256) void k_init(u64* packed, int n) {
    int i = blockIdx.x * 256 + threadIdx.x;
    if (i < n) packed[i] = 0ULL;
}

// One u64 atomic per edge: count in bits [40,64), fixed-point weight sum
// (2^24 scale) in bits [0,40). Old value >> 40 = this edge's rank in row.
__global__ __launch_bounds__(256) void k_edge_deg(const int* __restrict__ dst,
                                                  const float* __restrict__ w,
                                                  u64* __restrict__ packed,
                                                  unsigned int* __restrict__ rank, int E) {
    int e = blockIdx.x * 256 + threadIdx.x;
    if (e < E) {
        int d = dst[e];
        u64 add = (1ULL << 40) | (u64)(w[e] * 16777216.0f);
        u64 old = atomicAdd(&packed[d], add);
        rank[e] = (unsigned int)(old >> 40);
    }
}

// Phase 1: per-block sum of counts -> bsum[block]; fused dinv = rsqrt(deg).
__global__ __launch_bounds__(256) void k_part(const u64* __restrict__ packed,
                                              float* __restrict__ dinv,
                                              int* __restrict__ bsum, int n) {
    __shared__ int red[256];
    int t = threadIdx.x;
    int i = blockIdx.x * 256 + t;
    int c = 0;
    if (i < n) {
        u64 p = packed[i];
        c = (int)(p >> 40);
        float degsum = (float)(p & ((1ULL << 40) - 1)) * (1.0f / 16777216.0f);
        dinv[i] = rsqrtf(1.0f + degsum);   // self-loop weight 1
    }
    red[t] = c;
    __syncthreads();
#pragma unroll
    for (int off = 128; off > 0; off >>= 1) {
        if (t < off) red[t] += red[t + off];
        __syncthreads();
    }
    if (t == 0) bsum[blockIdx.x] = red[0];
}

// Phase 2: single block exclusive-scans bsum (nb <= 256 for N=50000).
__global__ __launch_bounds__(256) void k_scan_bsums(int* bsum, int nb) {
    __shared__ int s[256];
    int t = threadIdx.x;
    s[t] = (t < nb) ? bsum[t] : 0;
    __syncthreads();
#pragma unroll
    for (int off = 1; off < 256; off <<= 1) {
        int u = (t >= off) ? s[t - off] : 0;
        __syncthreads();
        s[t] += u;
        __syncthreads();
    }
    if (t < nb) bsum[t] = (t == 0) ? 0 : s[t - 1];
}

// Phase 3: block-local inclusive scan + bsum offset -> rowptr.
__global__ __launch_bounds__(256) void k_rowptr(const u64* __restrict__ packed,
                                                const int* __restrict__ bsum,
                                                int* __restrict__ rowptr, int n) {
    __shared__ int s[256];
    int t = threadIdx.x;
    int i = blockIdx.x * 256 + t;
    int c = (i < n) ? (int)(packed[i] >> 40) : 0;
    s[t] = c;
    __syncthreads();
#pragma unroll
    for (int off = 1; off < 256; off <<= 1) {
        int u = (t >= off) ? s[t - off] : 0;
        __syncthreads();
        s[t] += u;
        __syncthreads();
    }
    int excl = bsum[blockIdx.x] + s[t] - c;
    if (i < n) rowptr[i] = excl;
    if (i == n - 1) rowptr[n] = excl + c;
}

// Atomic-free scatter using precomputed ranks.
__global__ __launch_bounds__(256) void k_scatter(const int* __restrict__ src,
                                                 const int* __restrict__ dst,
                                                 const float* __restrict__ w,
                                                 const unsigned int* __restrict__ rank,
                                                 const float* __restrict__ dinv,
                                                 const int* __restrict__ rowptr,
                                                 int* __restrict__ col,
                                                 float* __restrict__ val, int E) {
    int e = blockIdx.x * 256 + threadIdx.x;
    if (e < E) {
        int s = src[e], d = dst[e];
        int p = rowptr[d] + (int)rank[e];
        col[p] = s;
        val[p] = dinv[s] * w[e] * dinv[d];
    }
}

// Transpose+convert the 3 weight matrices (fp32 [k][n]) -> fp16 Wt [n][k].
__global__ __launch_bounds__(256) void k_prepw(const float* __restrict__ W1,
                                               const float* __restrict__ W2,
                                               const float* __restrict__ Wfc,
                                               __half* __restrict__ Wt) {
    int i = blockIdx.x * 256 + threadIdx.x;   // 0..49151
    if (i >= 3 * 16384) return;
    int w = i >> 14, r = i & 16383;
    int nn = r >> 7, kk = r & 127;
    const float* W = (w == 0) ? W1 : (w == 1) ? W2 : Wfc;
    Wt[i] = __float2half(W[kk * 128 + nn]);
}

// MFMA GEMM: Y[r,:] = X[r,:] @ W (+bias). 64 rows/block = 4 waves x 16 rows.
// Wt is fp16 [n][k] (pre-transposed). A-frag: X[m=lane&15][k=quad*8+j];
// B-frag: Wt[n=lane&15][k=quad*8+j]; C: row=quad*4+reg, col=lane&15.
// LDS pad +8 halfs/row: lane stride 272B -> 2-way bank alias (free).
template <bool IN_FP32, bool OUT_HALF>
__global__ __launch_bounds__(256) void k_gemm_mfma(const void* __restrict__ Xv,
                                                   const __half* __restrict__ Wt,
                                                   const float* __restrict__ bias,
                                                   void* __restrict__ Yv, int n) {
    __shared__ __align__(16) _Float16 Ws[128][136];
    int t = threadIdx.x;
    for (int i = t; i < 2048; i += 256) {   // 2048 x 16B chunks = 128x128 halfs
        int r = i >> 4, c8 = (i & 15) << 3;
        *(f16x8*)&Ws[r][c8] = *(const f16x8*)((const _Float16*)Wt + r * 128 + c8);
    }
    __syncthreads();

    int wave = t >> 6, lane = t & 63;
    int quad = lane >> 4, fcol = lane & 15;
    int rowbase = blockIdx.x * 64 + wave * 16;
    int arow = rowbase + fcol;            // A-operand row for this lane

    f16x8 a[4];
#pragma unroll
    for (int c = 0; c < 4; c++) {
        int k0 = c * 32 + quad * 8;
        if (arow < n) {
            if (IN_FP32) {
                const float* p = (const float*)Xv + (size_t)arow * 128 + k0;
#pragma unroll
                for (int j = 0; j < 8; j++) a[c][j] = (_Float16)p[j];
            } else {
                a[c] = *(const f16x8*)((const _Float16*)Xv + (size_t)arow * 128 + k0);
            }
        } else {
            f16x8 z = {0, 0, 0, 0, 0, 0, 0, 0};
            a[c] = z;
        }
    }

    f32x4 acc[8];
#pragma unroll
    for (int c = 0; c < 8; c++) acc[c] = (f32x4){0.f, 0.f, 0.f, 0.f};

#pragma unroll
    for (int kc = 0; kc < 4; kc++) {
        int k0 = kc * 32 + quad * 8;
#pragma unroll
        for (int ct = 0; ct < 8; ct++) {
            f16x8 b = *(const f16x8*)&Ws[ct * 16 + fcol][k0];
            acc[ct] = __builtin_amdgcn_mfma_f32_16x16x32_f16(a[kc], b, acc[ct], 0, 0, 0);
        }
    }

#pragma unroll
    for (int reg = 0; reg < 4; reg++) {
        int gr = rowbase + quad * 4 + reg;
        if (gr < n) {
            if (OUT_HALF) {
                __half* Y = (__half*)Yv;
#pragma unroll
                for (int ct = 0; ct < 8; ct++)
                    Y[(size_t)gr * 128 + ct * 16 + fcol] = __float2half(acc[ct][reg]);
            } else {
                float* Y = (float*)Yv;
#pragma unroll
                for (int ct = 0; ct < 8; ct++)
                    Y[(size_t)gr * 128 + ct * 16 + fcol] = acc[ct][reg] + bias[ct * 16 + fcol];
            }
        }
    }
}

// One wave per node; lane holds 2 features as half2 (256B coalesced rows).
// Coop-load 64 col/val per row (1 coalesced load), __shfl-broadcast, gathers
// in batches of 8 in flight. Accumulate fp32, store fp16 + ReLU.
__global__ __launch_bounds__(256) void k_agg(const __half* __restrict__ H,
                                             const int* __restrict__ rowptr,
                                             const int* __restrict__ col,
                                             const float* __restrict__ val,
                                             const float* __restrict__ dinv,
                                             const float* __restrict__ bias,
                                             __half* __restrict__ out, int n) {
    int wid = (blockIdx.x * 256 + threadIdx.x) >> 6;
    int lane = threadIdx.x & 63;
    if (wid >= n) return;
    int i = __builtin_amdgcn_readfirstlane(wid);  // wave-uniform -> scalar loads
    float di = dinv[i];
    float2 h0 = __half22float2(((const __half2*)(H + (size_t)i * 128))[lane]);
    float w0 = di * di;
    float ax = w0 * h0.x, ay = w0 * h0.y;
    int e0 = rowptr[i], e1 = rowptr[i + 1];

    for (int base = e0; base < e1; base += 64) {
        int cnt = min(64, e1 - base);
        int myc = 0; float myv = 0.f;
        if (lane < cnt) { myc = col[base + lane]; myv = val[base + lane]; }
        int j = 0;
        for (; j + 8 <= cnt; j += 8) {
            float2 h[8];
            float v[8];
#pragma unroll
            for (int u = 0; u < 8; u++) {
                int s = __shfl(myc, j + u);
                v[u] = __shfl(myv, j + u);
                h[u] = __half22float2(((const __half2*)(H + (size_t)s * 128))[lane]);
            }
#pragma unroll
            for (int u = 0; u < 8; u++) {
                ax = fmaf(v[u], h[u].x, ax);
                ay = fmaf(v[u], h[u].y, ay);
            }
        }
        for (; j < cnt; j++) {
            int s = __shfl(myc, j);
            float v = __shfl(myv, j);
            float2 h = __half22float2(((const __half2*)(H + (size_t)s * 128))[lane]);
            ax = fmaf(v, h.x, ax);
            ay = fmaf(v, h.y, ay);
        }
    }
    float2 b = ((const float2*)bias)[lane];
    ax = fmaxf(ax + b.x, 0.f);
    ay = fmaxf(ay + b.y, 0.f);
    ((__half2*)(out + (size_t)i * 128))[lane] = __floats2half2_rn(ax, ay);
}

extern "C" void kernel_launch(void* const* d_in, const int* in_sizes, int n_in,
                              void* d_out, int out_size, void* d_ws, size_t ws_size,
                              hipStream_t stream) {
    const float* x   = (const float*)d_in[0];
    const float* ew  = (const float*)d_in[1];
    const float* W1  = (const float*)d_in[2];
    const float* b1  = (const float*)d_in[3];
    const float* W2  = (const float*)d_in[4];
    const float* b2  = (const float*)d_in[5];
    const float* Wfc = (const float*)d_in[6];
    const float* bfc = (const float*)d_in[7];
    const int* eidx  = (const int*)d_in[8];

    const int E = in_sizes[1];
    const int N = in_sizes[0] / 128;
    const int* src = eidx;       // edge_index row 0
    const int* dst = eidx + E;   // edge_index row 1

    char* ws = (char*)d_ws;
    size_t off = 0;
    auto alloc = [&](size_t bytes) -> void* {
        void* p = ws + off;
        off = (off + bytes + 255) & ~(size_t)255;
        return p;
    };
    int nb = (N + 255) / 256;    // 196 for N=50000 (must be <= 256)
    int eb = (E + 255) / 256;
    int gb = (N + 63) / 64;      // MFMA gemm: 64 rows/block
    int ab = (N * 64 + 255) / 256;
    int Npad = N + 64;           // pad ws feature buffers (OOB-guarded anyway)

    u64*   packed = (u64*)alloc((size_t)N * 8);
    float* dinv   = (float*)alloc((size_t)N * 4);
    int*   rowptr = (int*)alloc((size_t)(N + 1) * 4);
    int*   bsum   = (int*)alloc((size_t)nb * 4);
    unsigned int* rank = (unsigned int*)alloc((size_t)E * 4);
    int*   col    = (int*)alloc((size_t)E * 4);
    float* val    = (float*)alloc((size_t)E * 4);
    __half* Wt    = (__half*)alloc((size_t)3 * 16384 * 2);  // 3 fp16 [n][k]
    __half* bufH  = (__half*)alloc((size_t)Npad * 128 * 2); // gemm output
    __half* bufA  = (__half*)alloc((size_t)Npad * 128 * 2); // agg output

    // Graph prep (re-done every launch; no state caching)
    k_init<<<nb, 256, 0, stream>>>(packed, N);
    k_edge_deg<<<eb, 256, 0, stream>>>(dst, ew, packed, rank, E);
    k_part<<<nb, 256, 0, stream>>>(packed, dinv, bsum, N);
    k_scan_bsums<<<1, 256, 0, stream>>>(bsum, nb);
    k_rowptr<<<nb, 256, 0, stream>>>(packed, bsum, rowptr, N);
    k_scatter<<<eb, 256, 0, stream>>>(src, dst, ew, rank, dinv, rowptr, col, val, E);
    k_prepw<<<192, 256, 0, stream>>>(W1, W2, Wfc, Wt);

    // Layer 1: x(fp32) @ W1 -> fp16; agg fp16 -> fp16
    k_gemm_mfma<true, true><<<gb, 256, 0, stream>>>(x, Wt, nullptr, bufH, N);
    k_agg<<<ab, 256, 0, stream>>>(bufH, rowptr, col, val, dinv, b1, bufA, N);
    // Layer 2
    k_gemm_mfma<false, true><<<gb, 256, 0, stream>>>(bufA, Wt + 16384, nullptr, bufH, N);
    k_agg<<<ab, 256, 0, stream>>>(bufH, rowptr, col, val, dinv, b2, bufA, N);
    // FC: fp16 in, fp32 out + bias to d_out
    k_gemm_mfma<false, false><<<gb, 256, 0, stream>>>(bufA, Wt + 2 * 16384, bfc, d_out, N);
}